// Round 9
// baseline (101.786 us; speedup 1.0000x reference)
//
#include <hip/hip_runtime.h>
#include <hip/hip_bf16.h>

typedef __attribute__((ext_vector_type(8))) short bf16x8;
typedef __attribute__((ext_vector_type(4))) float f32x4;

constexpr int NB = 16, CIN = 256, COUT = 256, TDIM = 4096, KS = 3, PADV = 1;
constexpr int TT = 128;            // t per block
constexpr int BK = 64;             // K-step (64 channels of one tap)
constexpr int NSTEP = 12;          // 4 c-blocks x 3 taps
constexpr int WSPAN = 144;         // x-window elems per c-block (t-halo +-8)
constexpr int XPAD  = 152;         // padded row elems (304 B = 76 dw = free banks)

typedef __attribute__((address_space(1))) const unsigned int gu32;
typedef __attribute__((address_space(3))) unsigned int lu32;

static __device__ __forceinline__ ushort f2bf(float f) {
    union { __hip_bfloat16 h; ushort u; } cv;
    cv.h = __float2bfloat16(f);
    return cv.u;
}

// Step s = cb*3 + k covers channels [cb*64, cb*64+64) of tap k. Per-step LDS
// image PRE-swizzled so a linear global_load_lds lands such that byte
// (o*128 + oc*16)^((o&7)<<4) holds W[o][tap k][c0 + oc*8 .. +8].
__global__ __launch_bounds__(256) void prepack_w(const float* __restrict__ w,
                                                 __hip_bfloat16* __restrict__ wp) {
    int idx = blockIdx.x * 256 + threadIdx.x;      // NSTEP*COUT*BK = 196608
    if (idx >= NSTEP * COUT * BK) return;
    int e  = idx & 7;
    int j  = (idx >> 3) & 7;
    int o  = (idx >> 6) & (COUT - 1);
    int s  = idx >> 14;                            // 0..11
    int k  = s % 3;
    int c  = (s / 3) * 64 + ((j ^ (o & 7)) << 3) + e;
    wp[idx] = __float2bfloat16(w[(o * CIN + c) * KS + k]);
}

__global__ __launch_bounds__(512, 4) void deform_mfma(
    const float* __restrict__ x,              // (NB, CIN, TDIM)
    const float* __restrict__ off,            // (NB, 2*KS, TDIM, 1)
    const __hip_bfloat16* __restrict__ wp,    // swizzled pack, 384 KB
    const float* __restrict__ bias,           // (COUT)
    float* __restrict__ out)                  // (NB, COUT, TDIM)
{
    __shared__ ushort w_s[COUT * BK];       // 32 KB swizzled W image per step
    __shared__ ushort v_s[TT * BK];         // 16 KB swizzled V tile [t][c]
    __shared__ ushort xw[64 * XPAD];        // 19 KB x window [c][j], row 304 B
    __shared__ int2   sP[KS][TT];           // {jloc, wa|wb<<16} per (k,t) 3 KB

    const int tid = threadIdx.x;

    // XCD-chunked bijective swizzle: XCD q (= bid%8) owns batches {2q, 2q+1}.
    const int bid  = blockIdx.x;           // 0..511
    const int q    = bid & 7;
    const int r    = bid >> 3;             // 0..63
    const int b    = 2 * q + (r >> 5);
    const int tt0  = (r & 31) * TT;
    const int win_lo = tt0 - 8;

    // ---- Phase A: per-(k,t) window slot + pair-ordered bf16 weights ----
    if (tid < KS * TT) {
        int k = tid >> 7, j = tid & (TT - 1);
        int t = tt0 + j;
        float dyr = off[((b * 2 * KS + 2 * k) * TDIM) + t];
        float dxr = off[((b * 2 * KS + 2 * k + 1) * TDIM) + t];
        float dyk = dyr - (float)(k - PADV);
        float py  = (float)(t - PADV + k) + dyk;
        float i0f = floorf(py);
        float fr  = py - i0f;
        int i0 = (int)i0f, i1 = i0 + 1;
        float wx = fmaxf(0.0f, 1.0f - fabsf(dxr));
        float w0 = (1.0f - fr) * wx * ((i0 >= 0 && i0 < TDIM) ? 1.0f : 0.0f);
        float w1 = fr * wx * ((i1 >= 0 && i1 < TDIM) ? 1.0f : 0.0f);
        int base = min(max(i0, 0), TDIM - 2);
        // pair (x[base], x[base+1]); route w0/w1 onto it (verified R8):
        bool iA = (i0 == base);
        float wa = iA ? w0 : ((i0 + 1 == base) ? w1 : 0.0f);
        float wb = iA ? w1 : ((i0 == base + 1) ? w0 : 0.0f);
        int2 p;
        p.x = base - win_lo;               // jloc in [0, 142]
        p.y = (int)((unsigned)f2bf(wa) | ((unsigned)f2bf(wb) << 16));
        sP[k][j] = p;
    }

    const int wid    = tid >> 6;
    const int lane   = tid & 63;
    const int o_base = (wid >> 1) * 64;
    const int t_base = (wid & 1) * 64;
    const int lr     = lane & 15;
    const int lg     = lane >> 4;

    // xw staging decomposition: row c = tid>>3, 8 threads x 18 elems per row
    const int sc = tid >> 3;               // 0..63
    const int sj = (tid & 7) * 18;         // 0..126

    f32x4 acc[4][4];
    #pragma unroll
    for (int i = 0; i < 4; ++i)
        #pragma unroll
        for (int j = 0; j < 4; ++j) acc[i][j] = (f32x4)0.0f;

    const float* xb = x + (size_t)b * CIN * TDIM;

    for (int cb = 0; cb < 4; ++cb) {
        const int cbase = cb * 64;

        // ---- stage x window [c][j] (once per c-block), coalesced ----
        {
            const float* xr = xb + (size_t)(cbase + sc) * TDIM;
            char* xrow = (char*)xw + sc * (XPAD * 2);
            if (win_lo >= 0 && win_lo + WSPAN <= TDIM) {      // block-uniform
                const float* s = xr + win_lo + sj;
                #pragma unroll
                for (int i = 0; i < 9; ++i) {
                    float2 f = *(const float2*)(s + 2 * i);
                    unsigned int u = (unsigned)f2bf(f.x) | ((unsigned)f2bf(f.y) << 16);
                    *(unsigned int*)(xrow + (sj + 2 * i) * 2) = u;
                }
            } else {
                #pragma unroll
                for (int i = 0; i < 9; ++i) {
                    int a0 = min(max(win_lo + sj + 2 * i, 0), TDIM - 1);
                    int a1 = min(max(win_lo + sj + 2 * i + 1, 0), TDIM - 1);
                    unsigned int u = (unsigned)f2bf(xr[a0]) | ((unsigned)f2bf(xr[a1]) << 16);
                    *(unsigned int*)(xrow + (sj + 2 * i) * 2) = u;
                }
            }
        }
        __syncthreads();   // xw(cb) visible (also covers sP on cb=0)

        for (int k = 0; k < 3; ++k) {
            const int s_idx = cb * 3 + k;

            // ---- stage W: direct global->LDS DMA, pre-swizzled source ----
            {
                const char* gbase = (const char*)wp + (size_t)s_idx * 32768 + wid * 4096 + lane * 16;
                char* lbase = (char*)w_s + wid * 4096;   // wave-uniform
                #pragma unroll
                for (int i = 0; i < 4; ++i)
                    __builtin_amdgcn_global_load_lds((gu32*)(gbase + i * 1024),
                                                     (lu32*)(lbase + i * 1024), 16, 0, 0);
            }

            // ---- v-phase: build S in regs, v = x·S via MFMA, pack to v_s ----
            {
                const int t2 = wid * 16 + lr;          // this wave's t-tile col
                int2 e = sP[k][t2];                    // broadcast across lg
                const int jrel = e.x - wid * 16;       // in [0, 31)
                const ushort wa = (ushort)(e.y & 0xffff);
                const ushort wb = (ushort)((unsigned)e.y >> 16);
                const int d = jrel - lg * 8;           // position in this k-group
                bf16x8 sf;
                #pragma unroll
                for (int e2 = 0; e2 < 8; ++e2)
                    sf[e2] = (short)((d == e2) ? wa : ((d + 1 == e2) ? wb : (ushort)0));

                const int acol = (wid * 16 + lg * 8) * 2;   // j-window byte offset
                #pragma unroll
                for (int ct = 0; ct < 4; ++ct) {
                    bf16x8 af = *(const bf16x8*)((const char*)xw +
                                  (ct * 16 + lr) * (XPAD * 2) + acol);
                    f32x4 dfr = __builtin_amdgcn_mfma_f32_16x16x32_bf16(
                        af, sf, (f32x4)0.0f, 0, 0, 0);
                    // D: col=t2 (lane&15), row c = ct*16 + lg*4 + reg
                    unsigned int lo = (unsigned)f2bf(dfr[0]) | ((unsigned)f2bf(dfr[1]) << 16);
                    unsigned int hi = (unsigned)f2bf(dfr[2]) | ((unsigned)f2bf(dfr[3]) << 16);
                    int cbyte = (ct * 16 + lg * 4) * 2;
                    int b0 = (t2 * 128 + cbyte) ^ ((t2 & 7) << 4);
                    int b1 = (t2 * 128 + cbyte + 4) ^ ((t2 & 7) << 4);
                    *(unsigned int*)((char*)v_s + b0) = lo;
                    *(unsigned int*)((char*)v_s + b1) = hi;
                }
            }

            __syncthreads();   // drains W-DMA + v_s writes; tiles ready

            // ---- main MFMA: wave computes 64(o) x 64(t), K=64 ----
            #pragma unroll
            for (int kb = 0; kb < 2; ++kb) {
                const int kk = kb * 32 + lg * 8;
                bf16x8 bfr[4];
                #pragma unroll
                for (int nf = 0; nf < 4; ++nf) {
                    int tc = t_base + nf * 16 + lr;
                    int byte = (tc * (BK * 2) + kk * 2) ^ ((tc & 7) << 4);
                    bfr[nf] = *(const bf16x8*)((const char*)v_s + byte);
                }
                #pragma unroll
                for (int mf = 0; mf < 4; ++mf) {
                    int o  = o_base + mf * 16 + lr;
                    int byte = (o * (BK * 2) + kk * 2) ^ ((o & 7) << 4);
                    bf16x8 af = *(const bf16x8*)((const char*)w_s + byte);
                    #pragma unroll
                    for (int nf = 0; nf < 4; ++nf)
                        acc[mf][nf] = __builtin_amdgcn_mfma_f32_16x16x32_bf16(
                            af, bfr[nf], acc[mf][nf], 0, 0, 0);
                }
            }
            __syncthreads();   // frag reads done -> next step may overwrite
        }
    }

    // ---- Epilogue: D col = lane&15 (t), row = (lane>>4)*4 + reg (o) ----
    #pragma unroll
    for (int mf = 0; mf < 4; ++mf) {
        #pragma unroll
        for (int r2 = 0; r2 < 4; ++r2) {
            int o = o_base + mf * 16 + lg * 4 + r2;
            float bv = bias[o];
            float* orow = out + (size_t)(b * COUT + o) * TDIM + tt0 + t_base;
            #pragma unroll
            for (int nf = 0; nf < 4; ++nf)
                orow[nf * 16 + lr] = acc[mf][nf][r2] + bv;
        }
    }
}

extern "C" void kernel_launch(void* const* d_in, const int* in_sizes, int n_in,
                              void* d_out, int out_size, void* d_ws, size_t ws_size,
                              hipStream_t stream) {
    const float* x    = (const float*)d_in[0];
    const float* off  = (const float*)d_in[1];
    const float* w    = (const float*)d_in[2];
    const float* bias = (const float*)d_in[3];
    float* out = (float*)d_out;
    __hip_bfloat16* wp = (__hip_bfloat16*)d_ws;   // 384 KB swizzled pack

    prepack_w<<<dim3((NSTEP * COUT * BK + 255) / 256), dim3(256), 0, stream>>>(w, wp);

    dim3 grid(512);
    deform_mfma<<<grid, dim3(512), 0, stream>>>(x, off, wp, bias, out);
}

// Round 10
// 76.576 us; speedup vs baseline: 1.3292x; 1.3292x over previous
//
#include <hip/hip_runtime.h>
#include <hip/hip_bf16.h>

typedef __attribute__((ext_vector_type(8))) short bf16x8;
typedef __attribute__((ext_vector_type(4))) float f32x4;

constexpr int NB = 16, CIN = 256, COUT = 256, TDIM = 4096, KS = 3, PADV = 1;
constexpr int TT = 128;            // t per block
constexpr int BK = 64;             // K-step (64 channels of one tap)
constexpr int NSTEP = 12;          // 4 c-blocks x 3 taps

typedef __attribute__((address_space(1))) const unsigned int gu32;
typedef __attribute__((address_space(3))) unsigned int lu32;

static __device__ __forceinline__ ushort f2bf(float f) {
    union { __hip_bfloat16 h; ushort u; } cv;
    cv.h = __float2bfloat16(f);
    return cv.u;
}
static __device__ __forceinline__ float bf2f(ushort u) {
    union { unsigned int u32; float f; } cv;
    cv.u32 = ((unsigned int)u) << 16;
    return cv.f;
}

// Step s = cb*3 + k covers channels [cb*64, cb*64+64) of tap k. Per-step LDS
// image PRE-swizzled so a linear global_load_lds lands such that byte
// (o*128 + oc*16)^((o&7)<<4) holds W[o][tap k][c0 + oc*8 .. +8].
__global__ __launch_bounds__(256) void prepack_w(const float* __restrict__ w,
                                                 __hip_bfloat16* __restrict__ wp) {
    int idx = blockIdx.x * 256 + threadIdx.x;      // NSTEP*COUT*BK = 196608
    if (idx >= NSTEP * COUT * BK) return;
    int e  = idx & 7;
    int j  = (idx >> 3) & 7;
    int o  = (idx >> 6) & (COUT - 1);
    int s  = idx >> 14;                            // 0..11
    int k  = s % 3;
    int c  = (s / 3) * 64 + ((j ^ (o & 7)) << 3) + e;
    wp[idx] = __float2bfloat16(w[(o * CIN + c) * KS + k]);
}

// x (B,C,T) f32  ->  xT (B,T,C) bf16.  64c x 64t tile per block via LDS.
__global__ __launch_bounds__(256) void transpose_x(const float* __restrict__ x,
                                                   ushort* __restrict__ xT) {
    __shared__ ushort tile[64][72];    // [t][c], pad 8 to break pow2 stride
    const int b  = blockIdx.z;
    const int c0 = blockIdx.y * 64;
    const int t0 = blockIdx.x * 64;
    const int tid = threadIdx.x;
    {
        const int c  = tid >> 2;             // 0..63
        const int tq = (tid & 3) << 4;       // 0,16,32,48
        const float* src = x + ((size_t)(b * CIN + c0 + c)) * TDIM + t0 + tq;
        #pragma unroll
        for (int i = 0; i < 4; ++i) {
            float4 f = *(const float4*)(src + 4 * i);
            tile[tq + 4 * i + 0][c] = f2bf(f.x);
            tile[tq + 4 * i + 1][c] = f2bf(f.y);
            tile[tq + 4 * i + 2][c] = f2bf(f.z);
            tile[tq + 4 * i + 3][c] = f2bf(f.w);
        }
    }
    __syncthreads();
    {
        const int t = tid >> 2;              // 0..63
        const int q = tid & 3;               // 16-channel chunk
        const uint4* lp = (const uint4*)&tile[t][q * 16];   // 16B aligned
        uint4 v0 = lp[0], v1 = lp[1];
        uint4* dst = (uint4*)(xT + ((size_t)b * TDIM + t0 + t) * CIN + c0 + q * 16);
        dst[0] = v0;
        dst[1] = v1;
    }
}

// ---- main kernel: V-gather from transposed xT (4 x b128 per thread/step) ----
__global__ __launch_bounds__(512, 4) void deform_mfma_xt(
    const ushort* __restrict__ xT,            // (NB, TDIM, CIN) bf16
    const float* __restrict__ off,            // (NB, 2*KS, TDIM, 1)
    const __hip_bfloat16* __restrict__ wp,    // swizzled pack, 384 KB
    const float* __restrict__ bias,           // (COUT)
    float* __restrict__ out)                  // (NB, COUT, TDIM)
{
    __shared__ ushort w_s[COUT * BK];       // 32 KB swizzled W image per step
    __shared__ ushort v_s[TT * BK];         // 16 KB swizzled V tile [t][c]
    __shared__ int4   sP[KS][TT];           // {base, waf, wbf, -} per (k,t) 6 KB

    const int tid = threadIdx.x;

    // XCD-chunked bijective swizzle: XCD q (= bid%8) owns batches {2q, 2q+1}.
    const int bid  = blockIdx.x;           // 0..511
    const int q    = bid & 7;
    const int r    = bid >> 3;             // 0..63
    const int b    = 2 * q + (r >> 5);
    const int tt0  = (r & 31) * TT;

    // ---- Phase A: per-(k,t) base row + pair-ordered f32 weights ----
    if (tid < KS * TT) {
        int k = tid >> 7, j = tid & (TT - 1);
        int t = tt0 + j;
        float dyr = off[((b * 2 * KS + 2 * k) * TDIM) + t];
        float dxr = off[((b * 2 * KS + 2 * k + 1) * TDIM) + t];
        float dyk = dyr - (float)(k - PADV);
        float py  = (float)(t - PADV + k) + dyk;
        float i0f = floorf(py);
        float fr  = py - i0f;
        int i0 = (int)i0f, i1 = i0 + 1;
        float wx = fmaxf(0.0f, 1.0f - fabsf(dxr));
        float w0 = (1.0f - fr) * wx * ((i0 >= 0 && i0 < TDIM) ? 1.0f : 0.0f);
        float w1 = fr * wx * ((i1 >= 0 && i1 < TDIM) ? 1.0f : 0.0f);
        int base = min(max(i0, 0), TDIM - 2);
        // pair (x[base], x[base+1]); route w0/w1 onto it (R8-verified):
        bool iA = (i0 == base);
        float wa = iA ? w0 : ((i0 + 1 == base) ? w1 : 0.0f);
        float wb = iA ? w1 : ((i0 == base + 1) ? w0 : 0.0f);
        int4 p;
        p.x = base;
        p.y = __float_as_int(wa);
        p.z = __float_as_int(wb);
        p.w = 0;
        sP[k][j] = p;
    }

    const int wid    = tid >> 6;
    const int lane   = tid & 63;
    const int o_base = (wid >> 1) * 64;
    const int t_base = (wid & 1) * 64;
    const int lr     = lane & 15;
    const int lg     = lane >> 4;

    const int coct0 = tid >> 7;            // 0..3
    const int t     = tid & (TT - 1);
    const int vrow  = t * (BK * 2);
    const int vswz  = (t & 7) << 4;
    const int voff0 = (vrow + coct0 * 16) ^ vswz;
    const int voff1 = (vrow + (coct0 + 4) * 16) ^ vswz;

    f32x4 acc[4][4];
    #pragma unroll
    for (int i = 0; i < 4; ++i)
        #pragma unroll
        for (int j = 0; j < 4; ++j) acc[i][j] = (f32x4)0.0f;

    const ushort* xTb = xT + (size_t)b * TDIM * CIN;

    for (int cb = 0; cb < 4; ++cb) {
      const int cbase = cb * 64;
      for (int k = 0; k < 3; ++k) {
        const int s_idx = cb * 3 + k;
        __syncthreads();   // MFMA(prev) done -> LDS writable; sP visible (s=0)

        // ---- stage W: direct global->LDS DMA, pre-swizzled source ----
        {
            const char* gbase = (const char*)wp + (size_t)s_idx * 32768 + wid * 4096 + lane * 16;
            char* lbase = (char*)w_s + wid * 4096;   // wave-uniform
            #pragma unroll
            for (int i = 0; i < 4; ++i)
                __builtin_amdgcn_global_load_lds((gu32*)(gbase + i * 1024),
                                                 (lu32*)(lbase + i * 1024), 16, 0, 0);
        }

        // ---- stage V: 4 x b128 gather from xT + f32 interp + pack ----
        {
            int4 e = sP[k][t];
            const ushort* rowA = xTb + (size_t)e.x * CIN + cbase + coct0 * 8;
            bf16x8 a0 = *(const bf16x8*)rowA;             // j=base,   c..c+8
            bf16x8 a1 = *(const bf16x8*)(rowA + CIN);     // j=base+1, c..c+8
            bf16x8 b0 = *(const bf16x8*)(rowA + 32);      // j=base,   c+32..
            bf16x8 b1 = *(const bf16x8*)(rowA + CIN + 32);
            float wa = __int_as_float(e.y), wb = __int_as_float(e.z);
            bf16x8 pk0, pk1;
            #pragma unroll
            for (int i = 0; i < 8; ++i) {
                pk0[i] = (short)f2bf(bf2f((ushort)a0[i]) * wa + bf2f((ushort)a1[i]) * wb);
                pk1[i] = (short)f2bf(bf2f((ushort)b0[i]) * wa + bf2f((ushort)b1[i]) * wb);
            }
            *(bf16x8*)((char*)v_s + voff0) = pk0;
            *(bf16x8*)((char*)v_s + voff1) = pk1;
        }

        __syncthreads();   // drains W-DMA + v_s writes; tiles ready

        // ---- main MFMA: wave computes 64(o) x 64(t), K=64 ----
        #pragma unroll
        for (int kb = 0; kb < 2; ++kb) {
            const int kk = kb * 32 + lg * 8;
            bf16x8 bfr[4];
            #pragma unroll
            for (int nf = 0; nf < 4; ++nf) {
                int tc = t_base + nf * 16 + lr;
                int byte = (tc * (BK * 2) + kk * 2) ^ ((tc & 7) << 4);
                bfr[nf] = *(const bf16x8*)((const char*)v_s + byte);
            }
            #pragma unroll
            for (int mf = 0; mf < 4; ++mf) {
                int o  = o_base + mf * 16 + lr;
                int byte = (o * (BK * 2) + kk * 2) ^ ((o & 7) << 4);
                bf16x8 af = *(const bf16x8*)((const char*)w_s + byte);
                #pragma unroll
                for (int nf = 0; nf < 4; ++nf)
                    acc[mf][nf] = __builtin_amdgcn_mfma_f32_16x16x32_bf16(
                        af, bfr[nf], acc[mf][nf], 0, 0, 0);
            }
        }
      }
    }

    // ---- Epilogue: D col = lane&15 (t), row = (lane>>4)*4 + reg (o) ----
    #pragma unroll
    for (int mf = 0; mf < 4; ++mf) {
        #pragma unroll
        for (int r2 = 0; r2 < 4; ++r2) {
            int o = o_base + mf * 16 + lg * 4 + r2;
            float bv = bias[o];
            float* orow = out + (size_t)(b * COUT + o) * TDIM + tt0 + t_base;
            #pragma unroll
            for (int nf = 0; nf < 4; ++nf)
                orow[nf * 16 + lr] = acc[mf][nf][r2] + bv;
        }
    }
}

// ---- fallback (proven 81us R6 kernel): scalar gathers from x ----
__global__ __launch_bounds__(512, 4) void deform_mfma_gather(
    const float* __restrict__ x,
    const float* __restrict__ off,
    const __hip_bfloat16* __restrict__ wp,
    const float* __restrict__ bias,
    float* __restrict__ out)
{
    __shared__ ushort w_s[COUT * BK];
    __shared__ ushort v_s[TT * BK];
    __shared__ int4   sP[KS][TT];

    const int tid = threadIdx.x;
    const int bid  = blockIdx.x;
    const int q    = bid & 7;
    const int r    = bid >> 3;
    const int b    = 2 * q + (r >> 5);
    const int tt0  = (r & 31) * TT;

    if (tid < KS * TT) {
        int k = tid >> 7, j = tid & (TT - 1);
        int t = tt0 + j;
        float dyr = off[((b * 2 * KS + 2 * k) * TDIM) + t];
        float dxr = off[((b * 2 * KS + 2 * k + 1) * TDIM) + t];
        float py  = (float)(t - PADV + k) + dyr - (float)(k - PADV);
        float i0f = floorf(py);
        float fr  = py - i0f;
        int i0 = (int)i0f, i1 = i0 + 1;
        float wx = fmaxf(0.0f, 1.0f - fabsf(dxr));
        float w0 = (1.0f - fr) * wx * ((i0 >= 0 && i0 < TDIM) ? 1.0f : 0.0f);
        float w1 = fr * wx * ((i1 >= 0 && i1 < TDIM) ? 1.0f : 0.0f);
        int4 p;
        p.x = min(max(i0, 0), TDIM - 1);
        p.y = min(max(i1, 0), TDIM - 1);
        p.z = __float_as_int(w0);
        p.w = __float_as_int(w1);
        sP[k][j] = p;
    }

    const int wid    = tid >> 6;
    const int lane   = tid & 63;
    const int o_base = (wid >> 1) * 64;
    const int t_base = (wid & 1) * 64;
    const int lr     = lane & 15;
    const int lg     = lane >> 4;

    f32x4 acc[4][4];
    #pragma unroll
    for (int i = 0; i < 4; ++i)
        #pragma unroll
        for (int j = 0; j < 4; ++j) acc[i][j] = (f32x4)0.0f;

    const float* xb = x + (size_t)b * CIN * TDIM;

    for (int cb = 0; cb < 4; ++cb) {
      for (int k = 0; k < 3; ++k) {
        const int s_idx = cb * 3 + k;
        const int c0    = cb * 64;
        __syncthreads();
        {
            const char* gbase = (const char*)wp + (size_t)s_idx * 32768 + wid * 4096 + lane * 16;
            char* lbase = (char*)w_s + wid * 4096;
            #pragma unroll
            for (int i = 0; i < 4; ++i)
                __builtin_amdgcn_global_load_lds((gu32*)(gbase + i * 1024),
                                                 (lu32*)(lbase + i * 1024), 16, 0, 0);
        }
        {
            const int coct0 = tid >> 7;
            const int t     = tid & (TT - 1);
            int4 p = sP[k][t];
            const float* xr0 = xb + (size_t)(c0 + coct0 * 8) * TDIM;
            const float* xr1 = xr0 + (size_t)32 * TDIM;
            float g0[16], g1[16];
            #pragma unroll
            for (int i = 0; i < 8; ++i) {
                g0[2 * i]     = xr0[p.x];
                g0[2 * i + 1] = xr0[p.y];
                xr0 += TDIM;
            }
            #pragma unroll
            for (int i = 0; i < 8; ++i) {
                g1[2 * i]     = xr1[p.x];
                g1[2 * i + 1] = xr1[p.y];
                xr1 += TDIM;
            }
            float w0 = __int_as_float(p.z), w1 = __int_as_float(p.w);
            bf16x8 pk0, pk1;
            #pragma unroll
            for (int i = 0; i < 8; ++i) {
                pk0[i] = (short)f2bf(g0[2 * i] * w0 + g0[2 * i + 1] * w1);
                pk1[i] = (short)f2bf(g1[2 * i] * w0 + g1[2 * i + 1] * w1);
            }
            int row = t * (BK * 2);
            int swz = (t & 7) << 4;
            *(bf16x8*)((char*)v_s + ((row + coct0 * 16) ^ swz))       = pk0;
            *(bf16x8*)((char*)v_s + ((row + (coct0 + 4) * 16) ^ swz)) = pk1;
        }
        __syncthreads();
        #pragma unroll
        for (int kb = 0; kb < 2; ++kb) {
            const int kk = kb * 32 + lg * 8;
            bf16x8 bfr[4];
            #pragma unroll
            for (int nf = 0; nf < 4; ++nf) {
                int tc = t_base + nf * 16 + lr;
                int byte = (tc * (BK * 2) + kk * 2) ^ ((tc & 7) << 4);
                bfr[nf] = *(const bf16x8*)((const char*)v_s + byte);
            }
            #pragma unroll
            for (int mf = 0; mf < 4; ++mf) {
                int o  = o_base + mf * 16 + lr;
                int byte = (o * (BK * 2) + kk * 2) ^ ((o & 7) << 4);
                bf16x8 af = *(const bf16x8*)((const char*)w_s + byte);
                #pragma unroll
                for (int nf = 0; nf < 4; ++nf)
                    acc[mf][nf] = __builtin_amdgcn_mfma_f32_16x16x32_bf16(
                        af, bfr[nf], acc[mf][nf], 0, 0, 0);
            }
        }
      }
    }

    #pragma unroll
    for (int mf = 0; mf < 4; ++mf) {
        #pragma unroll
        for (int r2 = 0; r2 < 4; ++r2) {
            int o = o_base + mf * 16 + lg * 4 + r2;
            float bv = bias[o];
            float* orow = out + (size_t)(b * COUT + o) * TDIM + tt0 + t_base;
            #pragma unroll
            for (int nf = 0; nf < 4; ++nf)
                orow[nf * 16 + lr] = acc[mf][nf][r2] + bv;
        }
    }
}

extern "C" void kernel_launch(void* const* d_in, const int* in_sizes, int n_in,
                              void* d_out, int out_size, void* d_ws, size_t ws_size,
                              hipStream_t stream) {
    const float* x    = (const float*)d_in[0];
    const float* off  = (const float*)d_in[1];
    const float* w    = (const float*)d_in[2];
    const float* bias = (const float*)d_in[3];
    float* out = (float*)d_out;
    __hip_bfloat16* wp = (__hip_bfloat16*)d_ws;   // 384 KB swizzled pack

    prepack_w<<<dim3((NSTEP * COUT * BK + 255) / 256), dim3(256), 0, stream>>>(w, wp);

    const size_t xt_off  = 512 * 1024;
    const size_t xt_need = xt_off + (size_t)NB * TDIM * CIN * sizeof(ushort);

    if (ws_size >= xt_need) {
        ushort* xT = (ushort*)((char*)d_ws + xt_off);
        transpose_x<<<dim3(TDIM / 64, CIN / 64, NB), dim3(256), 0, stream>>>(x, xT);
        deform_mfma_xt<<<dim3(512), dim3(512), 0, stream>>>(xT, off, wp, bias, out);
    } else {
        deform_mfma_gather<<<dim3(512), dim3(512), 0, stream>>>(x, off, wp, bias, out);
    }
}

// Round 11
// 71.027 us; speedup vs baseline: 1.4331x; 1.0781x over previous
//
#include <hip/hip_runtime.h>
#include <hip/hip_bf16.h>

typedef __attribute__((ext_vector_type(8))) short bf16x8;
typedef __attribute__((ext_vector_type(4))) float f32x4;

constexpr int NB = 16, CIN = 256, COUT = 256, TDIM = 4096, KS = 3, PADV = 1;
constexpr int TT = 128;            // t per block
constexpr int BK = 64;             // K-step (64 channels of one tap)
constexpr int NSTEP = 12;          // 4 c-blocks x 3 taps

typedef __attribute__((address_space(1))) const unsigned int gu32;
typedef __attribute__((address_space(3))) unsigned int lu32;

static __device__ __forceinline__ ushort f2bf(float f) {
    union { __hip_bfloat16 h; ushort u; } cv;
    cv.h = __float2bfloat16(f);
    return cv.u;
}
static __device__ __forceinline__ float bf2f(ushort u) {
    union { unsigned int u32; float f; } cv;
    cv.u32 = ((unsigned int)u) << 16;
    return cv.f;
}

// Step s = cb*3 + k covers channels [cb*64, cb*64+64) of tap k. Per-step LDS
// image PRE-swizzled so a linear global_load_lds lands such that byte
// (o*128 + oc*16)^((o&7)<<4) holds W[o][tap k][c0 + oc*8 .. +8].
__global__ __launch_bounds__(256) void prepack_w(const float* __restrict__ w,
                                                 __hip_bfloat16* __restrict__ wp) {
    int idx = blockIdx.x * 256 + threadIdx.x;      // NSTEP*COUT*BK = 196608
    if (idx >= NSTEP * COUT * BK) return;
    int e  = idx & 7;
    int j  = (idx >> 3) & 7;
    int o  = (idx >> 6) & (COUT - 1);
    int s  = idx >> 14;                            // 0..11
    int k  = s % 3;
    int c  = (s / 3) * 64 + ((j ^ (o & 7)) << 3) + e;
    wp[idx] = __float2bfloat16(w[(o * CIN + c) * KS + k]);
}

// x (B,C,T) f32  ->  xT (B,T,C) bf16.  64c x 64t tile per block via LDS.
__global__ __launch_bounds__(256) void transpose_x(const float* __restrict__ x,
                                                   ushort* __restrict__ xT) {
    __shared__ ushort tile[64][72];    // [t][c], pad 8 to break pow2 stride
    const int b  = blockIdx.z;
    const int c0 = blockIdx.y * 64;
    const int t0 = blockIdx.x * 64;
    const int tid = threadIdx.x;
    {
        const int c  = tid >> 2;             // 0..63
        const int tq = (tid & 3) << 4;       // 0,16,32,48
        const float* src = x + ((size_t)(b * CIN + c0 + c)) * TDIM + t0 + tq;
        #pragma unroll
        for (int i = 0; i < 4; ++i) {
            float4 f = *(const float4*)(src + 4 * i);
            tile[tq + 4 * i + 0][c] = f2bf(f.x);
            tile[tq + 4 * i + 1][c] = f2bf(f.y);
            tile[tq + 4 * i + 2][c] = f2bf(f.z);
            tile[tq + 4 * i + 3][c] = f2bf(f.w);
        }
    }
    __syncthreads();
    {
        const int t = tid >> 2;              // 0..63
        const int q = tid & 3;               // 16-channel chunk
        const uint4* lp = (const uint4*)&tile[t][q * 16];   // 16B aligned
        uint4 v0 = lp[0], v1 = lp[1];
        uint4* dst = (uint4*)(xT + ((size_t)b * TDIM + t0 + t) * CIN + c0 + q * 16);
        dst[0] = v0;
        dst[1] = v1;
    }
}

// ---- main kernel: coalesced V-gather (8 lanes share one t) ----
__global__ __launch_bounds__(512, 4) void deform_mfma_xt(
    const ushort* __restrict__ xT,            // (NB, TDIM, CIN) bf16
    const float* __restrict__ off,            // (NB, 2*KS, TDIM, 1)
    const __hip_bfloat16* __restrict__ wp,    // swizzled pack, 384 KB
    const float* __restrict__ bias,           // (COUT)
    float* __restrict__ out)                  // (NB, COUT, TDIM)
{
    __shared__ ushort w_s[COUT * BK];       // 32 KB swizzled W image per step
    __shared__ ushort v_s[TT * BK];         // 16 KB swizzled V tile [t][c]
    __shared__ int4   sP[KS][TT];           // {base, waf, wbf, -} per (k,t) 6 KB

    const int tid = threadIdx.x;

    // XCD-chunked bijective swizzle: XCD q (= bid%8) owns batches {2q, 2q+1}.
    const int bid  = blockIdx.x;           // 0..511
    const int q    = bid & 7;
    const int r    = bid >> 3;             // 0..63
    const int b    = 2 * q + (r >> 5);
    const int tt0  = (r & 31) * TT;

    // ---- Phase A: per-(k,t) base row + pair-ordered f32 weights ----
    if (tid < KS * TT) {
        int k = tid >> 7, j = tid & (TT - 1);
        int t = tt0 + j;
        float dyr = off[((b * 2 * KS + 2 * k) * TDIM) + t];
        float dxr = off[((b * 2 * KS + 2 * k + 1) * TDIM) + t];
        float dyk = dyr - (float)(k - PADV);
        float py  = (float)(t - PADV + k) + dyk;
        float i0f = floorf(py);
        float fr  = py - i0f;
        int i0 = (int)i0f, i1 = i0 + 1;
        float wx = fmaxf(0.0f, 1.0f - fabsf(dxr));
        float w0 = (1.0f - fr) * wx * ((i0 >= 0 && i0 < TDIM) ? 1.0f : 0.0f);
        float w1 = fr * wx * ((i1 >= 0 && i1 < TDIM) ? 1.0f : 0.0f);
        int base = min(max(i0, 0), TDIM - 2);
        // pair (x[base], x[base+1]); route w0/w1 onto it (R8-verified):
        bool iA = (i0 == base);
        float wa = iA ? w0 : ((i0 + 1 == base) ? w1 : 0.0f);
        float wb = iA ? w1 : ((i0 == base + 1) ? w0 : 0.0f);
        int4 p;
        p.x = base;
        p.y = __float_as_int(wa);
        p.z = __float_as_int(wb);
        p.w = 0;
        sP[k][j] = p;
    }

    const int wid    = tid >> 6;
    const int lane   = tid & 63;
    const int o_base = (wid >> 1) * 64;
    const int t_base = (wid & 1) * 64;
    const int lr     = lane & 15;
    const int lg     = lane >> 4;

    // V-phase mapping: 8 lanes per t -> coalesced 128B row segments
    const int tg   = tid >> 3;             // 0..63  (t-group, pass adds 64)
    const int slot = tid & 7;              // 8-channel slot within 64-ch block
    const int t0l  = tg;                   // pass 0 t
    const int t1l  = tg + 64;              // pass 1 t
    const int voffA = (t0l * 128 + slot * 16) ^ ((t0l & 7) << 4);
    const int voffB = (t1l * 128 + slot * 16) ^ ((t1l & 7) << 4);

    f32x4 acc[4][4];
    #pragma unroll
    for (int i = 0; i < 4; ++i)
        #pragma unroll
        for (int j = 0; j < 4; ++j) acc[i][j] = (f32x4)0.0f;

    const ushort* xTb = xT + (size_t)b * TDIM * CIN;

    for (int cb = 0; cb < 4; ++cb) {
      const int cbase = cb * 64;
      for (int k = 0; k < 3; ++k) {
        const int s_idx = cb * 3 + k;
        __syncthreads();   // MFMA(prev) done -> LDS writable; sP visible (s=0)

        // ---- stage W: direct global->LDS DMA, pre-swizzled source ----
        {
            const char* gbase = (const char*)wp + (size_t)s_idx * 32768 + wid * 4096 + lane * 16;
            char* lbase = (char*)w_s + wid * 4096;   // wave-uniform
            #pragma unroll
            for (int i = 0; i < 4; ++i)
                __builtin_amdgcn_global_load_lds((gu32*)(gbase + i * 1024),
                                                 (lu32*)(lbase + i * 1024), 16, 0, 0);
        }

        // ---- stage V: coalesced b128 gathers (all 4 issued first) ----
        {
            int4 e0 = sP[k][t0l];
            int4 e1 = sP[k][t1l];
            const ushort* rowA = xTb + (size_t)e0.x * CIN + cbase + slot * 8;
            const ushort* rowB = xTb + (size_t)e1.x * CIN + cbase + slot * 8;
            bf16x8 a0 = *(const bf16x8*)rowA;             // t0: j=base
            bf16x8 a1 = *(const bf16x8*)(rowA + CIN);     // t0: j=base+1
            bf16x8 b0 = *(const bf16x8*)rowB;             // t1: j=base
            bf16x8 b1 = *(const bf16x8*)(rowB + CIN);     // t1: j=base+1
            float wa0 = __int_as_float(e0.y), wb0 = __int_as_float(e0.z);
            float wa1 = __int_as_float(e1.y), wb1 = __int_as_float(e1.z);
            bf16x8 pk0, pk1;
            #pragma unroll
            for (int i = 0; i < 8; ++i) {
                pk0[i] = (short)f2bf(bf2f((ushort)a0[i]) * wa0 + bf2f((ushort)a1[i]) * wb0);
                pk1[i] = (short)f2bf(bf2f((ushort)b0[i]) * wa1 + bf2f((ushort)b1[i]) * wb1);
            }
            *(bf16x8*)((char*)v_s + voffA) = pk0;
            *(bf16x8*)((char*)v_s + voffB) = pk1;
        }

        __syncthreads();   // drains W-DMA + v_s writes; tiles ready

        // ---- main MFMA: wave computes 64(o) x 64(t), K=64 ----
        #pragma unroll
        for (int kb = 0; kb < 2; ++kb) {
            const int kk = kb * 32 + lg * 8;
            bf16x8 bfr[4];
            #pragma unroll
            for (int nf = 0; nf < 4; ++nf) {
                int tc = t_base + nf * 16 + lr;
                int byte = (tc * (BK * 2) + kk * 2) ^ ((tc & 7) << 4);
                bfr[nf] = *(const bf16x8*)((const char*)v_s + byte);
            }
            #pragma unroll
            for (int mf = 0; mf < 4; ++mf) {
                int o  = o_base + mf * 16 + lr;
                int byte = (o * (BK * 2) + kk * 2) ^ ((o & 7) << 4);
                bf16x8 af = *(const bf16x8*)((const char*)w_s + byte);
                #pragma unroll
                for (int nf = 0; nf < 4; ++nf)
                    acc[mf][nf] = __builtin_amdgcn_mfma_f32_16x16x32_bf16(
                        af, bfr[nf], acc[mf][nf], 0, 0, 0);
            }
        }
      }
    }

    // ---- Epilogue: D col = lane&15 (t), row = (lane>>4)*4 + reg (o) ----
    #pragma unroll
    for (int mf = 0; mf < 4; ++mf) {
        #pragma unroll
        for (int r2 = 0; r2 < 4; ++r2) {
            int o = o_base + mf * 16 + lg * 4 + r2;
            float bv = bias[o];
            float* orow = out + (size_t)(b * COUT + o) * TDIM + tt0 + t_base;
            #pragma unroll
            for (int nf = 0; nf < 4; ++nf)
                orow[nf * 16 + lr] = acc[mf][nf][r2] + bv;
        }
    }
}

// ---- fallback (proven 81us R6 kernel): scalar gathers from x ----
__global__ __launch_bounds__(512, 4) void deform_mfma_gather(
    const float* __restrict__ x,
    const float* __restrict__ off,
    const __hip_bfloat16* __restrict__ wp,
    const float* __restrict__ bias,
    float* __restrict__ out)
{
    __shared__ ushort w_s[COUT * BK];
    __shared__ ushort v_s[TT * BK];
    __shared__ int4   sP[KS][TT];

    const int tid = threadIdx.x;
    const int bid  = blockIdx.x;
    const int q    = bid & 7;
    const int r    = bid >> 3;
    const int b    = 2 * q + (r >> 5);
    const int tt0  = (r & 31) * TT;

    if (tid < KS * TT) {
        int k = tid >> 7, j = tid & (TT - 1);
        int t = tt0 + j;
        float dyr = off[((b * 2 * KS + 2 * k) * TDIM) + t];
        float dxr = off[((b * 2 * KS + 2 * k + 1) * TDIM) + t];
        float py  = (float)(t - PADV + k) + dyr - (float)(k - PADV);
        float i0f = floorf(py);
        float fr  = py - i0f;
        int i0 = (int)i0f, i1 = i0 + 1;
        float wx = fmaxf(0.0f, 1.0f - fabsf(dxr));
        float w0 = (1.0f - fr) * wx * ((i0 >= 0 && i0 < TDIM) ? 1.0f : 0.0f);
        float w1 = fr * wx * ((i1 >= 0 && i1 < TDIM) ? 1.0f : 0.0f);
        int4 p;
        p.x = min(max(i0, 0), TDIM - 1);
        p.y = min(max(i1, 0), TDIM - 1);
        p.z = __float_as_int(w0);
        p.w = __float_as_int(w1);
        sP[k][j] = p;
    }

    const int wid    = tid >> 6;
    const int lane   = tid & 63;
    const int o_base = (wid >> 1) * 64;
    const int t_base = (wid & 1) * 64;
    const int lr     = lane & 15;
    const int lg     = lane >> 4;

    f32x4 acc[4][4];
    #pragma unroll
    for (int i = 0; i < 4; ++i)
        #pragma unroll
        for (int j = 0; j < 4; ++j) acc[i][j] = (f32x4)0.0f;

    const float* xb = x + (size_t)b * CIN * TDIM;

    for (int cb = 0; cb < 4; ++cb) {
      for (int k = 0; k < 3; ++k) {
        const int s_idx = cb * 3 + k;
        const int c0    = cb * 64;
        __syncthreads();
        {
            const char* gbase = (const char*)wp + (size_t)s_idx * 32768 + wid * 4096 + lane * 16;
            char* lbase = (char*)w_s + wid * 4096;
            #pragma unroll
            for (int i = 0; i < 4; ++i)
                __builtin_amdgcn_global_load_lds((gu32*)(gbase + i * 1024),
                                                 (lu32*)(lbase + i * 1024), 16, 0, 0);
        }
        {
            const int coct0 = tid >> 7;
            const int t     = tid & (TT - 1);
            int4 p = sP[k][t];
            const float* xr0 = xb + (size_t)(c0 + coct0 * 8) * TDIM;
            const float* xr1 = xr0 + (size_t)32 * TDIM;
            float g0[16], g1[16];
            #pragma unroll
            for (int i = 0; i < 8; ++i) {
                g0[2 * i]     = xr0[p.x];
                g0[2 * i + 1] = xr0[p.y];
                xr0 += TDIM;
            }
            #pragma unroll
            for (int i = 0; i < 8; ++i) {
                g1[2 * i]     = xr1[p.x];
                g1[2 * i + 1] = xr1[p.y];
                xr1 += TDIM;
            }
            float w0 = __int_as_float(p.z), w1 = __int_as_float(p.w);
            bf16x8 pk0, pk1;
            #pragma unroll
            for (int i = 0; i < 8; ++i) {
                pk0[i] = (short)f2bf(g0[2 * i] * w0 + g0[2 * i + 1] * w1);
                pk1[i] = (short)f2bf(g1[2 * i] * w0 + g1[2 * i + 1] * w1);
            }
            int row = t * (BK * 2);
            int swz = (t & 7) << 4;
            *(bf16x8*)((char*)v_s + ((row + coct0 * 16) ^ swz))       = pk0;
            *(bf16x8*)((char*)v_s + ((row + (coct0 + 4) * 16) ^ swz)) = pk1;
        }
        __syncthreads();
        #pragma unroll
        for (int kb = 0; kb < 2; ++kb) {
            const int kk = kb * 32 + lg * 8;
            bf16x8 bfr[4];
            #pragma unroll
            for (int nf = 0; nf < 4; ++nf) {
                int tc = t_base + nf * 16 + lr;
                int byte = (tc * (BK * 2) + kk * 2) ^ ((tc & 7) << 4);
                bfr[nf] = *(const bf16x8*)((const char*)v_s + byte);
            }
            #pragma unroll
            for (int mf = 0; mf < 4; ++mf) {
                int o  = o_base + mf * 16 + lr;
                int byte = (o * (BK * 2) + kk * 2) ^ ((o & 7) << 4);
                bf16x8 af = *(const bf16x8*)((const char*)w_s + byte);
                #pragma unroll
                for (int nf = 0; nf < 4; ++nf)
                    acc[mf][nf] = __builtin_amdgcn_mfma_f32_16x16x32_bf16(
                        af, bfr[nf], acc[mf][nf], 0, 0, 0);
            }
        }
      }
    }

    #pragma unroll
    for (int mf = 0; mf < 4; ++mf) {
        #pragma unroll
        for (int r2 = 0; r2 < 4; ++r2) {
            int o = o_base + mf * 16 + lg * 4 + r2;
            float bv = bias[o];
            float* orow = out + (size_t)(b * COUT + o) * TDIM + tt0 + t_base;
            #pragma unroll
            for (int nf = 0; nf < 4; ++nf)
                orow[nf * 16 + lr] = acc[mf][nf][r2] + bv;
        }
    }
}

extern "C" void kernel_launch(void* const* d_in, const int* in_sizes, int n_in,
                              void* d_out, int out_size, void* d_ws, size_t ws_size,
                              hipStream_t stream) {
    const float* x    = (const float*)d_in[0];
    const float* off  = (const float*)d_in[1];
    const float* w    = (const float*)d_in[2];
    const float* bias = (const float*)d_in[3];
    float* out = (float*)d_out;
    __hip_bfloat16* wp = (__hip_bfloat16*)d_ws;   // 384 KB swizzled pack

    prepack_w<<<dim3((NSTEP * COUT * BK + 255) / 256), dim3(256), 0, stream>>>(w, wp);

    const size_t xt_off  = 512 * 1024;
    const size_t xt_need = xt_off + (size_t)NB * TDIM * CIN * sizeof(ushort);

    if (ws_size >= xt_need) {
        ushort* xT = (ushort*)((char*)d_ws + xt_off);
        transpose_x<<<dim3(TDIM / 64, CIN / 64, NB), dim3(256), 0, stream>>>(x, xT);
        deform_mfma_xt<<<dim3(512), dim3(512), 0, stream>>>(xT, off, wp, bias, out);
    } else {
        deform_mfma_gather<<<dim3(512), dim3(512), 0, stream>>>(x, off, wp, bias, out);
    }
}